// Round 6
// baseline (607.237 us; speedup 1.0000x reference)
//
#include <hip/hip_runtime.h>
#include <hip/hip_bf16.h>

typedef __bf16 bf16_t;
typedef float  f32x4   __attribute__((ext_vector_type(4)));
typedef float  f32x16  __attribute__((ext_vector_type(16)));
typedef bf16_t bf16x4  __attribute__((ext_vector_type(4)));
typedef bf16_t bf16x8  __attribute__((ext_vector_type(8)));

#define MFMA16(a, b, c) __builtin_amdgcn_mfma_f32_16x16x32_bf16((a), (b), (c), 0, 0, 0)
#define MFMA32(a, b, c) __builtin_amdgcn_mfma_f32_32x32x16_bf16((a), (b), (c), 0, 0, 0)

#define GLOAD_LDS16(g, l)                                                              \
  __builtin_amdgcn_global_load_lds((const __attribute__((address_space(1))) void*)(g), \
                                   (__attribute__((address_space(3))) void*)(l), 16, 0, 0)

#define BARRIER    __builtin_amdgcn_s_barrier()
#define WAIT_LGKM0 asm volatile("s_waitcnt lgkmcnt(0)" ::: "memory")
#define WAIT_LGKM8 asm volatile("s_waitcnt lgkmcnt(8)" ::: "memory")
#define WAIT_VM4   asm volatile("s_waitcnt vmcnt(4)" ::: "memory")
#define WAIT_VM0   asm volatile("s_waitcnt vmcnt(0)" ::: "memory")

// ---------------- elementwise f32 -> bf16 ----------------
__global__ __launch_bounds__(256) void cvt_bf16(const float* __restrict__ in,
                                                bf16_t* __restrict__ out, int n4) {
  int stride = gridDim.x * blockDim.x;
  for (int i = blockIdx.x * blockDim.x + threadIdx.x; i < n4; i += stride) {
    f32x4 v = ((const f32x4*)in)[i];
    bf16x4 o;
#pragma unroll
    for (int j = 0; j < 4; ++j) o[j] = (bf16_t)v[j];
    ((bf16x4*)out)[i] = o;
  }
}

// ---------------- transpose + convert: in[R][C] f32 -> out[C][R] bf16 ----------------
__global__ __launch_bounds__(256) void transpose_cvt(const float* __restrict__ in,
                                                     bf16_t* __restrict__ out,
                                                     int R, int C) {
  __shared__ float t[64][65];
  int tr0 = blockIdx.y * 64, tc0 = blockIdx.x * 64;
  int tx = threadIdx.x & 15, ty = threadIdx.x >> 4;
#pragma unroll
  for (int i = 0; i < 4; ++i) {
    f32x4 v = *(const f32x4*)(in + (size_t)(tr0 + ty + 16 * i) * C + tc0 + tx * 4);
#pragma unroll
    for (int j = 0; j < 4; ++j) t[ty + 16 * i][tx * 4 + j] = v[j];
  }
  __syncthreads();
#pragma unroll
  for (int i = 0; i < 4; ++i) {
    bf16x4 o4;
#pragma unroll
    for (int j = 0; j < 4; ++j) o4[j] = (bf16_t)t[tx * 4 + j][ty + 16 * i];
    *(bf16x4*)(out + (size_t)(tc0 + ty + 16 * i) * R + tr0 + tx * 4) = o4;
  }
}

// ---------------- 256x256 8-phase GEMM, 32x32x16 MFMA: C = A * Bt^T ----------------
// 8 waves as 2M x 4N (per-wave 128x64 = 4mf32 x 2nf32). B frags once per K-tile
// (8 b128, ph1/ph5); A mf-block (4 b128) per phase. Stage rotation: A(o)@ph1-2,
// B(e')@ph3-4, A(e')@ph5-6, B(o')@ph7-8; vmcnt(4) at ph4/ph8. LDS 128KB swizzled.
// 32x32x16 frag: row = lane&31, k = ks*16 + (lane>>5)*8 (+j). row&7 == lane&7.
#define LDB8(bf)                                                                         \
  {                                                                                      \
    const int sb_ = bBase0 + (bf)*16384;                                                 \
    _Pragma("unroll") for (int nf = 0; nf < 2; ++nf) {                                   \
      int row_ = brow0 + nf * 32 + li31;                                                 \
      _Pragma("unroll") for (int ks = 0; ks < 4; ++ks)                                   \
          b[nf][ks] = *(const bf16x8*)&lds[sb_ + row_ * 64 + ((ks * 16 + hi8) ^ co)];    \
    }                                                                                    \
  }

#define LDA4(bf, q)                                                                      \
  {                                                                                      \
    const int sb_ = aBase0 + (bf)*16384;                                                 \
    const int row_ = (q)*32 + li31;                                                      \
    _Pragma("unroll") for (int ks = 0; ks < 4; ++ks)                                     \
        a[ks] = *(const bf16x8*)&lds[sb_ + row_ * 64 + ((ks * 16 + hi8) ^ co)];          \
  }

#define MMQ(q)                                                                           \
  {                                                                                      \
    __builtin_amdgcn_s_setprio(1);                                                       \
    _Pragma("unroll") for (int nf = 0; nf < 2; ++nf)                                     \
        _Pragma("unroll") for (int ks = 0; ks < 4; ++ks)                                 \
            acc[q][nf] = MFMA32(a[ks], b[nf][ks], acc[q][nf]);                           \
    __builtin_amdgcn_s_setprio(0);                                                       \
  }

template <int WRITE_BF16>
__global__ __launch_bounds__(512) void gemm8(const bf16_t* __restrict__ A,
                                             const bf16_t* __restrict__ Bt,
                                             void* __restrict__ Cv,
                                             int N, int K, int ntn) {
  __shared__ alignas(16) bf16_t lds[65536];  // A: [0,32768), B: [32768,65536)
  const int tid = threadIdx.x;
  const int lane = tid & 63, w = tid >> 6;
  const int wr = w >> 2, wc = w & 3;  // 2 M-waves x 4 N-waves
  const int li31 = lane & 31, hi8 = (lane >> 5) * 8;
  const int cpx = gridDim.x >> 3;  // XCD-bijective swizzle (gridDim.x % 8 == 0)
  const int wg = ((int)blockIdx.x & 7) * cpx + ((int)blockIdx.x >> 3);
  const int m0 = (wg / ntn) * 256, n0 = (wg % ntn) * 256;
  const int ksw = ((lane & 7) ^ (lane >> 3)) << 3;  // swizzled source granule
  const int aBase0 = wr * 8192;
  const int bBase0 = 32768 + (wc >> 1) * 8192;
  const int brow0 = (wc & 1) * 64;
  const int co = (lane & 7) << 3;

  const bf16_t* As[2] = {A + (size_t)m0 * K, A + (size_t)(m0 + 128) * K};
  const bf16_t* Bs[2] = {Bt + (size_t)n0 * K, Bt + (size_t)(n0 + 128) * K};

  auto stage = [&](const bf16_t* src, int kk, int ldsbase) {  // 128 rows x 64 k
#pragma unroll
    for (int j = 0; j < 2; ++j)
      GLOAD_LDS16(src + (size_t)(j * 64 + w * 8 + (lane >> 3)) * K + kk + ksw,
                  (char*)&lds[ldsbase + (j * 64 + w * 8) * 64]);
  };

  bf16x8 a[4], b[2][4];
  f32x16 acc[4][2];
#pragma unroll
  for (int mf = 0; mf < 4; ++mf)
#pragma unroll
    for (int nf = 0; nf < 2; ++nf)
#pragma unroll
      for (int e = 0; e < 16; ++e) acc[mf][nf][e] = 0.f;

  // ---- prologue: buf0 = K-tile 0 (A+B), plus B of K-tile 64 (buf1) ----
  stage(As[0], 0, 0);
  stage(As[1], 0, 8192);
  stage(Bs[0], 0, 32768);
  stage(Bs[1], 0, 40960);
  stage(Bs[0], 64, 49152);
  stage(Bs[1], 64, 57344);
  WAIT_VM4;  // drain buf0's 4 stages; B(64) stays in flight
  BARRIER;

  const int NT2 = K >> 7;
  for (int i = 0; i < NT2; ++i) {
    const int keb = i << 7;
    const int kA1 = keb + 64;
    int e2 = keb + 128;
    if (e2 > K - 64) e2 = K - 64;
    int o2 = keb + 192;
    if (o2 > K - 64) o2 = K - 64;
    // ph1: buf0 q0 (a + all b = 12 reads); stage A(odd,h0) -> buf1
    LDA4(0, 0) LDB8(0)
    stage(As[0], kA1, 16384);
    WAIT_LGKM8;
    BARRIER; WAIT_LGKM0;
    MMQ(0)
    BARRIER;
    // ph2: buf0 q1; stage A(odd,h1)
    LDA4(0, 1)
    stage(As[1], kA1, 24576);
    BARRIER; WAIT_LGKM0;
    MMQ(1)
    BARRIER;
    // ph3: buf0 q2; stage B(e',h0)
    LDA4(0, 2)
    stage(Bs[0], e2, 32768);
    BARRIER; WAIT_LGKM0;
    MMQ(2)
    BARRIER;
    // ph4: buf0 q3; stage B(e',h1); vmcnt(4) readies buf1
    LDA4(0, 3)
    stage(Bs[1], e2, 40960);
    BARRIER; WAIT_LGKM0;
    MMQ(3)
    WAIT_VM4;
    BARRIER;
    // ph5: buf1 q0 (a + b); stage A(e',h0) -> buf0
    LDA4(1, 0) LDB8(1)
    stage(As[0], e2, 0);
    WAIT_LGKM8;
    BARRIER; WAIT_LGKM0;
    MMQ(0)
    BARRIER;
    // ph6: buf1 q1; stage A(e',h1)
    LDA4(1, 1)
    stage(As[1], e2, 8192);
    BARRIER; WAIT_LGKM0;
    MMQ(1)
    BARRIER;
    // ph7: buf1 q2; stage B(o',h0) -> buf1
    LDA4(1, 2)
    stage(Bs[0], o2, 49152);
    BARRIER; WAIT_LGKM0;
    MMQ(2)
    BARRIER;
    // ph8: buf1 q3; stage B(o',h1); vmcnt(4) readies buf0
    LDA4(1, 3)
    stage(Bs[1], o2, 57344);
    BARRIER; WAIT_LGKM0;
    MMQ(3)
    WAIT_VM4;
    BARRIER;
  }
  WAIT_VM0;

  // ---- epilogue: 32x32 D col = l&31, row = (reg&3) + 8*(reg>>2) + 4*(l>>5) ----
#pragma unroll
  for (int mf = 0; mf < 4; ++mf) {
#pragma unroll
    for (int nf = 0; nf < 2; ++nf) {
      int gcol = n0 + wc * 64 + nf * 32 + li31;
#pragma unroll
      for (int r = 0; r < 16; ++r) {
        int grow = m0 + wr * 128 + mf * 32 + (r & 3) + 8 * (r >> 2) + (hi8 >> 1);
        if (WRITE_BF16)
          ((bf16_t*)Cv)[(size_t)grow * N + gcol] = (bf16_t)acc[mf][nf][r];
        else
          ((float*)Cv)[(size_t)grow * N + gcol] = acc[mf][nf][r];
      }
    }
  }
}

// ---------------- RoPE + repack: fused QKV [token][6144] -> per-head [B,H,N,D] ----------------
__global__ __launch_bounds__(256) void rope_pack(const bf16_t* __restrict__ QKV,
                                                 const int* __restrict__ pos,
                                                 bf16_t* __restrict__ Qr,
                                                 bf16_t* __restrict__ Kr,
                                                 bf16_t* __restrict__ Vr) {
  int unit = blockIdx.x * 4 + (threadIdx.x >> 6);
  int lane = threadIdx.x & 63;
  int token = unit / 48, slot = unit % 48;
  int b = token >> 11, n = token & 2047;
  const bf16_t* base = QKV + (size_t)token * 6144;
  if (slot < 40) {
    float p = (float)pos[token];
    float inv = exp2f(-(float)lane * 0.20762050593045702f);
    float ang = p * inv;
    float sn, cs;
    sincosf(ang, &sn, &cs);
    const bf16_t* src;
    bf16_t* dst;
    if (slot < 32) {
      src = base + slot * 128;
      dst = Qr + ((size_t)(b * 32 + slot) * 2048 + n) * 128;
    } else {
      int kvh = slot - 32;
      src = base + 4096 + kvh * 128;
      dst = Kr + ((size_t)(b * 8 + kvh) * 2048 + n) * 128;
    }
    float x0 = (float)src[lane], x1 = (float)src[lane + 64];
    dst[lane] = (bf16_t)(x0 * cs - x1 * sn);
    dst[lane + 64] = (bf16_t)(x1 * cs + x0 * sn);
  } else {
    int kvh = slot - 40;
    const bf16_t* src = base + 5120 + kvh * 128;
    bf16_t* dst = Vr + ((size_t)(b * 8 + kvh) * 2048 + n) * 128;
    dst[lane] = src[lane];
    dst[lane + 64] = src[lane + 64];
  }
}

// ---------------- flash attention: 8 waves/block, paired q-tiles, T14 async-stage ----
__global__ __launch_bounds__(512) void attn_kernel(const bf16_t* __restrict__ Q,
                                                   const bf16_t* __restrict__ K,
                                                   const bf16_t* __restrict__ V,
                                                   bf16_t* __restrict__ O) {
  const float scale = 0.08838834764831845f;  // 1/sqrt(128)
  __shared__ alignas(16) bf16_t Kl[64 * 128];    // swizzled [kv][d]
  __shared__ alignas(16) bf16_t Vt[128 * 64];    // swizzled [d][kv]
  __shared__ alignas(16) bf16_t Pl[8][32 * 64];  // per-wave swizzled [q][kv]
  const int tid = threadIdx.x;
  const int lane = tid & 63, w = tid >> 6;
  const int g = lane >> 4, ci = lane & 15;
  const int hb = blockIdx.y;  // b*32 + h
  const int b = hb >> 5, h = hb & 31, kvh = h >> 2;
  const int p = blockIdx.x;  // pair index 0..7
  const int qtB = 15 - p;
  const int qr[2] = {p * 128 + w * 16, qtB * 128 + w * 16};
  const bf16_t* Qh = Q + (size_t)hb * 2048 * 128;
  const bf16_t* Kh = K + (size_t)(b * 8 + kvh) * 2048 * 128;
  const bf16_t* Vh = V + (size_t)(b * 8 + kvh) * 2048 * 128;

  bf16x8 bq[2][4];
#pragma unroll
  for (int qb = 0; qb < 2; ++qb)
#pragma unroll
    for (int ks = 0; ks < 4; ++ks)
      bq[qb][ks] = *(const bf16x8*)(Qh + (size_t)(qr[qb] + ci) * 128 + ks * 32 + g * 8);

  f32x4 o[2][8];
#pragma unroll
  for (int qb = 0; qb < 2; ++qb)
#pragma unroll
    for (int nb = 0; nb < 8; ++nb) o[qb][nb] = f32x4{0.f, 0.f, 0.f, 0.f};
  float mrow[2] = {-1e30f, -1e30f};
  float lrow[2] = {0.f, 0.f};

  // T14 async-stage state: K tile (2x bf16x8) + V tile (4x bf16x4) in regs
  bf16x8 kreg[2];
  bf16x4 rv[4];
  const int kq = tid >> 5, dq = tid & 31;
  auto loadKV = [&](int kv0) {
#pragma unroll
    for (int i = 0; i < 2; ++i) {
      int c = tid + i * 512;
      kreg[i] = *(const bf16x8*)(Kh + (size_t)(kv0 + (c >> 4)) * 128 + (c & 15) * 8);
    }
#pragma unroll
    for (int rr = 0; rr < 4; ++rr)
      rv[rr] = *(const bf16x4*)(Vh + (size_t)(kv0 + kq * 4 + rr) * 128 + dq * 4);
  };
  auto writeKV = [&]() {
#pragma unroll
    for (int i = 0; i < 2; ++i) {
      int c = tid + i * 512;
      int row = c >> 4, kc = (c & 15) * 8;
      int sw = ((row ^ (row >> 3)) & 7) << 4;
      *(bf16x8*)((char*)Kl + row * 256 + ((kc * 2) ^ sw)) = kreg[i];
    }
#pragma unroll
    for (int jj = 0; jj < 4; ++jj) {
      int d = dq * 4 + jj;
      bf16x4 cv;
#pragma unroll
      for (int rr = 0; rr < 4; ++rr) cv[rr] = rv[rr][jj];
      int sw = ((d ^ (d >> 3)) & 7) << 4;
      *(bf16x4*)((char*)Vt + d * 128 + ((kq * 8) ^ sw)) = cv;
    }
  };

  const int nt = (qtB + 1) * 2;
  loadKV(0);
  for (int t = 0; t < nt; ++t) {
    const int kv0 = t * 64;
    __syncthreads();   // prev compute done; drains in-flight global loads too
    writeKV();
    __syncthreads();
    if (t + 1 < nt) loadKV(kv0 + 64);  // issue early; lands under compute

    bool act[2] = {kv0 <= qr[0] + 15, kv0 <= qr[1] + 15};
#pragma unroll
    for (int qb = 0; qb < 2; ++qb) {
      if (!act[qb]) continue;
      f32x4 st[4];
#pragma unroll
      for (int kvb = 0; kvb < 4; ++kvb) st[kvb] = f32x4{0.f, 0.f, 0.f, 0.f};
      __builtin_amdgcn_s_setprio(1);
#pragma unroll
      for (int kvb = 0; kvb < 4; ++kvb) {
        int row = kvb * 16 + ci;
        int sw = ((row ^ (row >> 3)) & 7) << 4;
#pragma unroll
        for (int ks = 0; ks < 4; ++ks) {
          bf16x8 ak = *(const bf16x8*)((char*)Kl + row * 256 + ((ks * 64 + g * 16) ^ sw));
          st[kvb] = MFMA16(ak, bq[qb][ks], st[kvb]);
        }
      }
      __builtin_amdgcn_s_setprio(0);
      const int q = qr[qb] + ci;
      const bool needmask = (kv0 + 63 > qr[qb]);
      float pv[16];
      float pm = -1e30f;
#pragma unroll
      for (int kvb = 0; kvb < 4; ++kvb)
#pragma unroll
        for (int r = 0; r < 4; ++r) {
          float v = st[kvb][r] * scale;
          if (needmask && (kv0 + kvb * 16 + 4 * g + r > q)) v = -1e30f;
          pv[kvb * 4 + r] = v;
          pm = fmaxf(pm, v);
        }
      pm = fmaxf(pm, __shfl_xor(pm, 16));
      pm = fmaxf(pm, __shfl_xor(pm, 32));
      // T13 defer-max
      const bool nskip = !__all((int)(pm <= mrow[qb] + 8.0f));
      const float mold = mrow[qb];
      float mnew = mold;
      float fs = 1.0f;
      if (nskip) {
        mnew = fmaxf(mold, pm);
        fs = __expf(mold - mnew);
        mrow[qb] = mnew;
      }
      float ps = 0.f;
#pragma unroll
      for (int e = 0; e < 16; ++e) {
        pv[e] = __expf(pv[e] - mnew);
        ps += pv[e];
      }
      ps += __shfl_xor(ps, 16);
      ps += __shfl_xor(ps, 32);
      lrow[qb] = (nskip ? lrow[qb] * fs : lrow[qb]) + ps;
      int prow = qb * 16 + ci;
      int swp = ((prow ^ (prow >> 3)) & 7) << 4;
#pragma unroll
      for (int kvb = 0; kvb < 4; ++kvb) {
        bf16x4 pk;
#pragma unroll
        for (int r = 0; r < 4; ++r) pk[r] = (bf16_t)pv[kvb * 4 + r];
        *(bf16x4*)((char*)&Pl[w][0] + prow * 128 + (((kvb * 16 + 4 * g) * 2) ^ swp)) = pk;
      }
      if (nskip) {
        float fo[4];
#pragma unroll
        for (int r = 0; r < 4; ++r) fo[r] = __shfl(fs, 4 * g + r);
#pragma unroll
        for (int nb = 0; nb < 8; ++nb)
#pragma unroll
          for (int r = 0; r < 4; ++r) o[qb][nb][r] *= fo[r];
      }
    }
    bf16x8 pa[2][2];
#pragma unroll
    for (int qb = 0; qb < 2; ++qb) {
      if (!act[qb]) continue;
      int prow = qb * 16 + ci;
      int swp = ((prow ^ (prow >> 3)) & 7) << 4;
#pragma unroll
      for (int ks = 0; ks < 2; ++ks)
        pa[qb][ks] = *(const bf16x8*)((char*)&Pl[w][0] + prow * 128 + ((ks * 64 + g * 16) ^ swp));
    }
    __builtin_amdgcn_s_setprio(1);
#pragma unroll
    for (int nb = 0; nb < 8; ++nb) {
      int d = nb * 16 + ci;
      int sw = ((d ^ (d >> 3)) & 7) << 4;
      bf16x8 bv0 = *(const bf16x8*)((char*)Vt + d * 128 + ((g * 16) ^ sw));
      bf16x8 bv1 = *(const bf16x8*)((char*)Vt + d * 128 + ((64 + g * 16) ^ sw));
#pragma unroll
      for (int qb = 0; qb < 2; ++qb) {
        if (!act[qb]) continue;
        o[qb][nb] = MFMA16(pa[qb][0], bv0, o[qb][nb]);
        o[qb][nb] = MFMA16(pa[qb][1], bv1, o[qb][nb]);
      }
    }
    __builtin_amdgcn_s_setprio(0);
  }
#pragma unroll
  for (int qb = 0; qb < 2; ++qb) {
    float linv = 1.0f / lrow[qb];
    float lv[4];
#pragma unroll
    for (int r = 0; r < 4; ++r) lv[r] = __shfl(linv, 4 * g + r);
#pragma unroll
    for (int r = 0; r < 4; ++r) {
      int n = qr[qb] + 4 * g + r;
      bf16_t* op = O + (size_t)(b * 2048 + n) * 4096 + h * 128;
#pragma unroll
      for (int nb = 0; nb < 8; ++nb) op[nb * 16 + ci] = (bf16_t)(o[qb][nb][r] * lv[r]);
    }
  }
}

extern "C" void kernel_launch(void* const* d_in, const int* in_sizes, int n_in,
                              void* d_out, int out_size, void* d_ws, size_t ws_size,
                              hipStream_t stream) {
  (void)in_sizes; (void)n_in; (void)out_size; (void)ws_size;
  const float* X = (const float*)d_in[0];
  const int* pos = (const int*)d_in[1];
  const float* Wq = (const float*)d_in[2];
  const float* Wk = (const float*)d_in[3];
  const float* Wv = (const float*)d_in[4];
  const float* Wo = (const float*)d_in[5];
  float* out = (float*)d_out;

  char* w = (char*)d_ws;
  auto carve = [&](size_t bytes) {
    void* p = (void*)w;
    w += (bytes + 255) & ~(size_t)255;
    return p;
  };
  const size_t T = 4096;  // B*N tokens
  bf16_t* Xbf    = (bf16_t*)carve(T * 4096 * 2);
  bf16_t* WqkvT  = (bf16_t*)carve(6144ull * 4096 * 2);  // [Wq;Wk;Wv] transposed
  bf16_t* WoT    = (bf16_t*)carve(4096ull * 4096 * 2);
  bf16_t* QKVraw = (bf16_t*)carve(T * 6144 * 2);
  bf16_t* Qr     = (bf16_t*)carve(T * 4096 * 2);
  bf16_t* Kr     = (bf16_t*)carve(T * 1024 * 2);
  bf16_t* Vr     = (bf16_t*)carve(T * 1024 * 2);
  bf16_t* Obf    = (bf16_t*)carve(T * 4096 * 2);

  cvt_bf16<<<2048, 256, 0, stream>>>(X, Xbf, (int)(T * 4096 / 4));
  transpose_cvt<<<dim3(64, 64), 256, 0, stream>>>(Wq, WqkvT, 4096, 4096);
  transpose_cvt<<<dim3(16, 64), 256, 0, stream>>>(Wk, WqkvT + 4096ull * 4096, 4096, 1024);
  transpose_cvt<<<dim3(16, 64), 256, 0, stream>>>(Wv, WqkvT + 5120ull * 4096, 4096, 1024);
  transpose_cvt<<<dim3(64, 64), 256, 0, stream>>>(Wo, WoT, 4096, 4096);

  // fused QKV projection: [4096 tokens][6144], 16x24 tiles of 256^2
  gemm8<1><<<384, 512, 0, stream>>>(Xbf, WqkvT, QKVraw, 6144, 4096, 24);

  rope_pack<<<(int)(T * 48 / 4), 256, 0, stream>>>(QKVraw, pos, Qr, Kr, Vr);

  attn_kernel<<<dim3(8, 64), 512, 0, stream>>>(Qr, Kr, Vr, Obf);

  // O projection: 16x16 tiles of 256^2
  gemm8<0><<<256, 512, 0, stream>>>(Obf, WoT, out, 4096, 4096, 16);
}

// Round 7
// 540.420 us; speedup vs baseline: 1.1236x; 1.1236x over previous
//
#include <hip/hip_runtime.h>
#include <hip/hip_bf16.h>

typedef __bf16 bf16_t;
typedef float  f32x4  __attribute__((ext_vector_type(4)));
typedef bf16_t bf16x4 __attribute__((ext_vector_type(4)));
typedef bf16_t bf16x8 __attribute__((ext_vector_type(8)));

#define MFMA16(a, b, c) __builtin_amdgcn_mfma_f32_16x16x32_bf16((a), (b), (c), 0, 0, 0)

#define GLOAD_LDS16(g, l)                                                              \
  __builtin_amdgcn_global_load_lds((const __attribute__((address_space(1))) void*)(g), \
                                   (__attribute__((address_space(3))) void*)(l), 16, 0, 0)

#define BARRIER    __builtin_amdgcn_s_barrier()
#define WAIT_LGKM0 asm volatile("s_waitcnt lgkmcnt(0)" ::: "memory")
#define WAIT_LGKM8 asm volatile("s_waitcnt lgkmcnt(8)" ::: "memory")
#define WAIT_VM3   asm volatile("s_waitcnt vmcnt(3)" ::: "memory")
#define WAIT_VM4   asm volatile("s_waitcnt vmcnt(4)" ::: "memory")
#define WAIT_VM0   asm volatile("s_waitcnt vmcnt(0)" ::: "memory")

// ---------------- elementwise f32 -> bf16 ----------------
__global__ __launch_bounds__(256) void cvt_bf16(const float* __restrict__ in,
                                                bf16_t* __restrict__ out, int n4) {
  int stride = gridDim.x * blockDim.x;
  for (int i = blockIdx.x * blockDim.x + threadIdx.x; i < n4; i += stride) {
    f32x4 v = ((const f32x4*)in)[i];
    bf16x4 o;
#pragma unroll
    for (int j = 0; j < 4; ++j) o[j] = (bf16_t)v[j];
    ((bf16x4*)out)[i] = o;
  }
}

// ---------------- transpose + convert: in[R][C] f32 -> out[C][R] bf16 ----------------
__global__ __launch_bounds__(256) void transpose_cvt(const float* __restrict__ in,
                                                     bf16_t* __restrict__ out,
                                                     int R, int C) {
  __shared__ float t[64][65];
  int tr0 = blockIdx.y * 64, tc0 = blockIdx.x * 64;
  int tx = threadIdx.x & 15, ty = threadIdx.x >> 4;
#pragma unroll
  for (int i = 0; i < 4; ++i) {
    f32x4 v = *(const f32x4*)(in + (size_t)(tr0 + ty + 16 * i) * C + tc0 + tx * 4);
#pragma unroll
    for (int j = 0; j < 4; ++j) t[ty + 16 * i][tx * 4 + j] = v[j];
  }
  __syncthreads();
#pragma unroll
  for (int i = 0; i < 4; ++i) {
    bf16x4 o4;
#pragma unroll
    for (int j = 0; j < 4; ++j) o4[j] = (bf16_t)t[tx * 4 + j][ty + 16 * i];
    *(bf16x4*)(out + (size_t)(tc0 + ty + 16 * i) * R + tr0 + tx * 4) = o4;
  }
}

// ================= 256x256 8-phase GEMM, 16x16x32 (O-projection) =================
#define LDB8(bf)                                                                         \
  {                                                                                      \
    const int sb_ = bBase0 + (bf)*16384;                                                 \
    _Pragma("unroll") for (int nf = 0; nf < 4; ++nf) {                                   \
      int row_ = brow0 + nf * 16 + ci;                                                   \
      _Pragma("unroll") for (int ks = 0; ks < 2; ++ks)                                   \
          b[nf][ks] = *(const bf16x8*)&lds[sb_ + row_ * 64 + ((ks * 32 + g * 8) ^ co)];  \
    }                                                                                    \
  }

#define LDA4(bf, q)                                                                      \
  {                                                                                      \
    const int sb_ = aBase0 + (bf)*16384;                                                 \
    _Pragma("unroll") for (int j = 0; j < 2; ++j) {                                      \
      int row_ = ((q)*2 + j) * 16 + ci;                                                  \
      _Pragma("unroll") for (int ks = 0; ks < 2; ++ks)                                   \
          a[j][ks] = *(const bf16x8*)&lds[sb_ + row_ * 64 + ((ks * 32 + g * 8) ^ co)];   \
    }                                                                                    \
  }

#define MMQ(q)                                                                           \
  {                                                                                      \
    __builtin_amdgcn_s_setprio(1);                                                       \
    _Pragma("unroll") for (int j = 0; j < 2; ++j)                                        \
        _Pragma("unroll") for (int nf = 0; nf < 4; ++nf)                                 \
            _Pragma("unroll") for (int ks = 0; ks < 2; ++ks)                             \
                acc[(q)*2 + j][nf] = MFMA16(a[j][ks], b[nf][ks], acc[(q)*2 + j][nf]);    \
    __builtin_amdgcn_s_setprio(0);                                                       \
  }

template <int WRITE_BF16>
__global__ __launch_bounds__(512) void gemm8o(const bf16_t* __restrict__ A,
                                              const bf16_t* __restrict__ Bt,
                                              void* __restrict__ Cv,
                                              int N, int K, int ntn) {
  __shared__ alignas(16) bf16_t lds[65536];  // A: [0,32768), B: [32768,65536)
  const int tid = threadIdx.x;
  const int lane = tid & 63, w = tid >> 6;
  const int wr = w >> 2, wc = w & 3;  // 2 M-waves x 4 N-waves
  const int g = lane >> 4, ci = lane & 15;
  const int cpx = gridDim.x >> 3;
  const int wg = ((int)blockIdx.x & 7) * cpx + ((int)blockIdx.x >> 3);
  const int m0 = (wg / ntn) * 256, n0 = (wg % ntn) * 256;
  const int ksw = ((lane & 7) ^ (lane >> 3)) << 3;
  const int aBase0 = wr * 8192;
  const int bBase0 = 32768 + (wc >> 1) * 8192;
  const int brow0 = (wc & 1) * 64;
  const int co = (ci & 7) << 3;

  const bf16_t* As[2] = {A + (size_t)m0 * K, A + (size_t)(m0 + 128) * K};
  const bf16_t* Bs[2] = {Bt + (size_t)n0 * K, Bt + (size_t)(n0 + 128) * K};

  auto stage = [&](const bf16_t* src, int kk, int ldsbase) {  // 128 rows x 64 k
#pragma unroll
    for (int j = 0; j < 2; ++j)
      GLOAD_LDS16(src + (size_t)(j * 64 + w * 8 + (lane >> 3)) * K + kk + ksw,
                  (char*)&lds[ldsbase + (j * 64 + w * 8) * 64]);
  };

  bf16x8 a[2][2], b[4][2];
  f32x4 acc[8][4];
#pragma unroll
  for (int mf = 0; mf < 8; ++mf)
#pragma unroll
    for (int nf = 0; nf < 4; ++nf) acc[mf][nf] = f32x4{0.f, 0.f, 0.f, 0.f};

  stage(As[0], 0, 0);
  stage(As[1], 0, 8192);
  stage(Bs[0], 0, 32768);
  stage(Bs[1], 0, 40960);
  stage(Bs[0], 64, 49152);
  stage(Bs[1], 64, 57344);
  WAIT_VM4;
  BARRIER;

  const int NT2 = K >> 7;
  for (int i = 0; i < NT2; ++i) {
    const int keb = i << 7;
    const int kA1 = keb + 64;
    int e2 = keb + 128;
    if (e2 > K - 64) e2 = K - 64;
    int o2 = keb + 192;
    if (o2 > K - 64) o2 = K - 64;
    LDA4(0, 0) LDB8(0)
    stage(As[0], kA1, 16384);
    WAIT_LGKM8;
    BARRIER; WAIT_LGKM0;
    MMQ(0)
    BARRIER;
    LDA4(0, 1)
    stage(As[1], kA1, 24576);
    BARRIER; WAIT_LGKM0;
    MMQ(1)
    BARRIER;
    LDA4(0, 2)
    stage(Bs[0], e2, 32768);
    BARRIER; WAIT_LGKM0;
    MMQ(2)
    BARRIER;
    LDA4(0, 3)
    stage(Bs[1], e2, 40960);
    BARRIER; WAIT_LGKM0;
    MMQ(3)
    WAIT_VM4;
    BARRIER;
    LDA4(1, 0) LDB8(1)
    stage(As[0], e2, 0);
    WAIT_LGKM8;
    BARRIER; WAIT_LGKM0;
    MMQ(0)
    BARRIER;
    LDA4(1, 1)
    stage(As[1], e2, 8192);
    BARRIER; WAIT_LGKM0;
    MMQ(1)
    BARRIER;
    LDA4(1, 2)
    stage(Bs[0], o2, 49152);
    BARRIER; WAIT_LGKM0;
    MMQ(2)
    BARRIER;
    LDA4(1, 3)
    stage(Bs[1], o2, 57344);
    BARRIER; WAIT_LGKM0;
    MMQ(3)
    WAIT_VM4;
    BARRIER;
  }
  WAIT_VM0;

#pragma unroll
  for (int mf = 0; mf < 8; ++mf) {
#pragma unroll
    for (int nf = 0; nf < 4; ++nf) {
      int grow = m0 + wr * 128 + mf * 16 + g * 4;
      int gcol = n0 + wc * 64 + nf * 16 + ci;
#pragma unroll
      for (int r = 0; r < 4; ++r) {
        if (WRITE_BF16)
          ((bf16_t*)Cv)[(size_t)(grow + r) * N + gcol] = (bf16_t)acc[mf][nf][r];
        else
          ((float*)Cv)[(size_t)(grow + r) * N + gcol] = acc[mf][nf][r];
      }
    }
  }
}

// ================= 256x192 8-phase GEMM, 16x16x32 (QKV, 512 blocks = 2 exact rounds) ==
// 8 waves as 4M x 2N (per-wave 64x96: mf fixed per phase, nf=6). BK=64, 2 K-tiles/iter.
// Stage granularity 64 rows (1 gload/thread): A = 4 calls/K-tile, B = 3.
// Rotation: A(o)@ph1-2, B(e')@ph3-4, A(e')@ph5-6, B(o')@ph7-8; vmcnt(3) at ph4/ph8.
// LDS: A buf0 [0,16384), A buf1 [16384,32768), B buf0 [32768,45056), B buf1 [45056,57344).
#define QLDB12(bf)                                                                        \
  {                                                                                       \
    const int sb_ = 32768 + (bf)*12288;                                                   \
    _Pragma("unroll") for (int nf = 0; nf < 6; ++nf) {                                    \
      int row_ = wc * 96 + nf * 16 + ci;                                                  \
      _Pragma("unroll") for (int ks = 0; ks < 2; ++ks)                                    \
          b[nf][ks] = *(const bf16x8*)&lds[sb_ + row_ * 64 + ((ks * 32 + g * 8) ^ co)];   \
    }                                                                                     \
  }

#define QLDA2(bf, q)                                                                      \
  {                                                                                       \
    const int sb_ = (bf)*16384;                                                           \
    const int row_ = wr * 64 + (q)*16 + ci;                                               \
    _Pragma("unroll") for (int ks = 0; ks < 2; ++ks)                                      \
        a[ks] = *(const bf16x8*)&lds[sb_ + row_ * 64 + ((ks * 32 + g * 8) ^ co)];         \
  }

#define QMMQ(q)                                                                           \
  {                                                                                       \
    __builtin_amdgcn_s_setprio(1);                                                        \
    _Pragma("unroll") for (int nf = 0; nf < 6; ++nf)                                      \
        _Pragma("unroll") for (int ks = 0; ks < 2; ++ks)                                  \
            acc[q][nf] = MFMA16(a[ks], b[nf][ks], acc[q][nf]);                            \
    __builtin_amdgcn_s_setprio(0);                                                        \
  }

__global__ __launch_bounds__(512) void gemm8qkv(const bf16_t* __restrict__ A,
                                                const bf16_t* __restrict__ Bt,
                                                bf16_t* __restrict__ C,
                                                int N, int K, int ntn) {
  __shared__ alignas(16) bf16_t lds[57344];
  const int tid = threadIdx.x;
  const int lane = tid & 63, w = tid >> 6;
  const int wr = w >> 1, wc = w & 1;  // 4 M-waves x 2 N-waves
  const int g = lane >> 4, ci = lane & 15;
  const int cpx = gridDim.x >> 3;
  const int wg = ((int)blockIdx.x & 7) * cpx + ((int)blockIdx.x >> 3);
  const int m0 = (wg / ntn) * 256, n0 = (wg % ntn) * 192;
  const int ksw = ((lane & 7) ^ (lane >> 3)) << 3;
  const int co = (ci & 7) << 3;

  const bf16_t* Ar[4] = {A + (size_t)m0 * K, A + (size_t)(m0 + 64) * K,
                         A + (size_t)(m0 + 128) * K, A + (size_t)(m0 + 192) * K};
  const bf16_t* Br[3] = {Bt + (size_t)n0 * K, Bt + (size_t)(n0 + 64) * K,
                         Bt + (size_t)(n0 + 128) * K};

  auto stage64 = [&](const bf16_t* src, int kk, int ldsbase) {  // 64 rows x 64 k
    GLOAD_LDS16(src + (size_t)(w * 8 + (lane >> 3)) * K + kk + ksw,
                (char*)&lds[ldsbase + w * 512]);
  };

  bf16x8 a[2], b[6][2];
  f32x4 acc[4][6];
#pragma unroll
  for (int mf = 0; mf < 4; ++mf)
#pragma unroll
    for (int nf = 0; nf < 6; ++nf) acc[mf][nf] = f32x4{0.f, 0.f, 0.f, 0.f};

  // prologue: buf0 A (4) + buf0 B (3) + buf1 B @k=64 (3); drain first 7
#pragma unroll
  for (int c = 0; c < 4; ++c) stage64(Ar[c], 0, c * 4096);
#pragma unroll
  for (int c = 0; c < 3; ++c) stage64(Br[c], 0, 32768 + c * 4096);
#pragma unroll
  for (int c = 0; c < 3; ++c) stage64(Br[c], 64, 45056 + c * 4096);
  WAIT_VM3;
  BARRIER;

  const int NT2 = K >> 7;
  for (int i = 0; i < NT2; ++i) {
    const int keb = i << 7;
    const int kA1 = keb + 64;
    int e2 = keb + 128;
    if (e2 > K - 64) e2 = K - 64;
    int o2 = keb + 192;
    if (o2 > K - 64) o2 = K - 64;
    // ph1: buf0 q0 (2+12 reads); stage A(o) c0,c1 -> buf1
    QLDA2(0, 0) QLDB12(0)
    stage64(Ar[0], kA1, 16384);
    stage64(Ar[1], kA1, 16384 + 4096);
    WAIT_LGKM8;
    BARRIER; WAIT_LGKM0;
    QMMQ(0)
    BARRIER;
    // ph2: buf0 q1; stage A(o) c2,c3
    QLDA2(0, 1)
    stage64(Ar[2], kA1, 16384 + 8192);
    stage64(Ar[3], kA1, 16384 + 12288);
    BARRIER; WAIT_LGKM0;
    QMMQ(1)
    BARRIER;
    // ph3: buf0 q2; stage B(e') c0,c1 -> buf0 B
    QLDA2(0, 2)
    stage64(Br[0], e2, 32768);
    stage64(Br[1], e2, 32768 + 4096);
    BARRIER; WAIT_LGKM0;
    QMMQ(2)
    BARRIER;
    // ph4: buf0 q3; stage B(e') c2; vmcnt(3) -> A(o)+B(o) complete for ph5
    QLDA2(0, 3)
    stage64(Br[2], e2, 32768 + 8192);
    BARRIER; WAIT_LGKM0;
    QMMQ(3)
    WAIT_VM3;
    BARRIER;
    // ph5: buf1 q0; stage A(e') c0,c1 -> buf0 A
    QLDA2(1, 0) QLDB12(1)
    stage64(Ar[0], e2, 0);
    stage64(Ar[1], e2, 4096);
    WAIT_LGKM8;
    BARRIER; WAIT_LGKM0;
    QMMQ(0)
    BARRIER;
    // ph6: buf1 q1; stage A(e') c2,c3
    QLDA2(1, 1)
    stage64(Ar[2], e2, 8192);
    stage64(Ar[3], e2, 12288);
    BARRIER; WAIT_LGKM0;
    QMMQ(1)
    BARRIER;
    // ph7: buf1 q2; stage B(o') c0,c1 -> buf1 B
    QLDA2(1, 2)
    stage64(Br[0], o2, 45056);
    stage64(Br[1], o2, 45056 + 4096);
    BARRIER; WAIT_LGKM0;
    QMMQ(2)
    BARRIER;
    // ph8: buf1 q3; stage B(o') c2; vmcnt(3) -> A(e')+B(e') complete for next ph1
    QLDA2(1, 3)
    stage64(Br[2], o2, 45056 + 8192);
    BARRIER; WAIT_LGKM0;
    QMMQ(3)
    WAIT_VM3;
    BARRIER;
  }
  WAIT_VM0;

  // epilogue: D row = (l>>4)*4 + r, col = l&15
#pragma unroll
  for (int mf = 0; mf < 4; ++mf) {
#pragma unroll
    for (int nf = 0; nf < 6; ++nf) {
      int grow = m0 + wr * 64 + mf * 16 + g * 4;
      int gcol = n0 + wc * 96 + nf * 16 + ci;
#pragma unroll
      for (int r = 0; r < 4; ++r)
        C[(size_t)(grow + r) * N + gcol] = (bf16_t)acc[mf][nf][r];
    }
  }
}

// ---------------- RoPE + repack: fused QKV [token][6144] -> per-head [B,H,N,D] ----------------
__global__ __launch_bounds__(256) void rope_pack(const bf16_t* __restrict__ QKV,
                                                 const int* __restrict__ pos,
                                                 bf16_t* __restrict__ Qr,
                                                 bf16_t* __restrict__ Kr,
                                                 bf16_t* __restrict__ Vr) {
  int unit = blockIdx.x * 4 + (threadIdx.x >> 6);
  int lane = threadIdx.x & 63;
  int token = unit / 48, slot = unit % 48;
  int b = token >> 11, n = token & 2047;
  const bf16_t* base = QKV + (size_t)token * 6144;
  if (slot < 40) {
    float p = (float)pos[token];
    float inv = exp2f(-(float)lane * 0.20762050593045702f);
    float ang = p * inv;
    float sn, cs;
    sincosf(ang, &sn, &cs);
    const bf16_t* src;
    bf16_t* dst;
    if (slot < 32) {
      src = base + slot * 128;
      dst = Qr + ((size_t)(b * 32 + slot) * 2048 + n) * 128;
    } else {
      int kvh = slot - 32;
      src = base + 4096 + kvh * 128;
      dst = Kr + ((size_t)(b * 8 + kvh) * 2048 + n) * 128;
    }
    float x0 = (float)src[lane], x1 = (float)src[lane + 64];
    dst[lane] = (bf16_t)(x0 * cs - x1 * sn);
    dst[lane + 64] = (bf16_t)(x1 * cs + x0 * sn);
  } else {
    int kvh = slot - 40;
    const bf16_t* src = base + 5120 + kvh * 128;
    bf16_t* dst = Vr + ((size_t)(b * 8 + kvh) * 2048 + n) * 128;
    dst[lane] = src[lane];
    dst[lane + 64] = src[lane + 64];
  }
}

// ---------------- flash attention: 8 waves/block, paired q-tiles, T14 async-stage ----
__global__ __launch_bounds__(512) void attn_kernel(const bf16_t* __restrict__ Q,
                                                   const bf16_t* __restrict__ K,
                                                   const bf16_t* __restrict__ V,
                                                   bf16_t* __restrict__ O) {
  const float scale = 0.08838834764831845f;  // 1/sqrt(128)
  __shared__ alignas(16) bf16_t Kl[64 * 128];    // swizzled [kv][d]
  __shared__ alignas(16) bf16_t Vt[128 * 64];    // swizzled [d][kv]
  __shared__ alignas(16) bf16_t Pl[8][32 * 64];  // per-wave swizzled [q][kv]
  const int tid = threadIdx.x;
  const int lane = tid & 63, w = tid >> 6;
  const int g = lane >> 4, ci = lane & 15;
  const int hb = blockIdx.y;  // b*32 + h
  const int b = hb >> 5, h = hb & 31, kvh = h >> 2;
  const int p = blockIdx.x;  // pair index 0..7
  const int qtB = 15 - p;
  const int qr[2] = {p * 128 + w * 16, qtB * 128 + w * 16};
  const bf16_t* Qh = Q + (size_t)hb * 2048 * 128;
  const bf16_t* Kh = K + (size_t)(b * 8 + kvh) * 2048 * 128;
  const bf16_t* Vh = V + (size_t)(b * 8 + kvh) * 2048 * 128;

  bf16x8 bq[2][4];
#pragma unroll
  for (int qb = 0; qb < 2; ++qb)
#pragma unroll
    for (int ks = 0; ks < 4; ++ks)
      bq[qb][ks] = *(const bf16x8*)(Qh + (size_t)(qr[qb] + ci) * 128 + ks * 32 + g * 8);

  f32x4 o[2][8];
#pragma unroll
  for (int qb = 0; qb < 2; ++qb)
#pragma unroll
    for (int nb = 0; nb < 8; ++nb) o[qb][nb] = f32x4{0.f, 0.f, 0.f, 0.f};
  float mrow[2] = {-1e30f, -1e30f};
  float lrow[2] = {0.f, 0.f};

  bf16x8 kreg[2];
  bf16x4 rv[4];
  const int kq = tid >> 5, dq = tid & 31;
  auto loadKV = [&](int kv0) {
#pragma unroll
    for (int i = 0; i < 2; ++i) {
      int c = tid + i * 512;
      kreg[i] = *(const bf16x8*)(Kh + (size_t)(kv0 + (c >> 4)) * 128 + (c & 15) * 8);
    }
#pragma unroll
    for (int rr = 0; rr < 4; ++rr)
      rv[rr] = *(const bf16x4*)(Vh + (size_t)(kv0 + kq * 4 + rr) * 128 + dq * 4);
  };
  auto writeKV = [&]() {
#pragma unroll
    for (int i = 0; i < 2; ++i) {
      int c = tid + i * 512;
      int row = c >> 4, kc = (c & 15) * 8;
      int sw = ((row ^ (row >> 3)) & 7) << 4;
      *(bf16x8*)((char*)Kl + row * 256 + ((kc * 2) ^ sw)) = kreg[i];
    }
#pragma unroll
    for (int jj = 0; jj < 4; ++jj) {
      int d = dq * 4 + jj;
      bf16x4 cv;
#pragma unroll
      for (int rr = 0; rr < 4; ++rr) cv[rr] = rv[rr][jj];
      int sw = ((d ^ (d >> 3)) & 7) << 4;
      *(bf16x4*)((char*)Vt + d * 128 + ((kq * 8) ^ sw)) = cv;
    }
  };

  const int nt = (qtB + 1) * 2;
  loadKV(0);
  for (int t = 0; t < nt; ++t) {
    const int kv0 = t * 64;
    __syncthreads();
    writeKV();
    __syncthreads();
    if (t + 1 < nt) loadKV(kv0 + 64);

    bool act[2] = {kv0 <= qr[0] + 15, kv0 <= qr[1] + 15};
#pragma unroll
    for (int qb = 0; qb < 2; ++qb) {
      if (!act[qb]) continue;
      f32x4 st[4];
#pragma unroll
      for (int kvb = 0; kvb < 4; ++kvb) st[kvb] = f32x4{0.f, 0.f, 0.f, 0.f};
      __builtin_amdgcn_s_setprio(1);
#pragma unroll
      for (int kvb = 0; kvb < 4; ++kvb) {
        int row = kvb * 16 + ci;
        int sw = ((row ^ (row >> 3)) & 7) << 4;
#pragma unroll
        for (int ks = 0; ks < 4; ++ks) {
          bf16x8 ak = *(const bf16x8*)((char*)Kl + row * 256 + ((ks * 64 + g * 16) ^ sw));
          st[kvb] = MFMA16(ak, bq[qb][ks], st[kvb]);
        }
      }
      __builtin_amdgcn_s_setprio(0);
      const int q = qr[qb] + ci;
      const bool needmask = (kv0 + 63 > qr[qb]);
      float pv[16];
      float pm = -1e30f;
#pragma unroll
      for (int kvb = 0; kvb < 4; ++kvb)
#pragma unroll
        for (int r = 0; r < 4; ++r) {
          float v = st[kvb][r] * scale;
          if (needmask && (kv0 + kvb * 16 + 4 * g + r > q)) v = -1e30f;
          pv[kvb * 4 + r] = v;
          pm = fmaxf(pm, v);
        }
      pm = fmaxf(pm, __shfl_xor(pm, 16));
      pm = fmaxf(pm, __shfl_xor(pm, 32));
      const bool nskip = !__all((int)(pm <= mrow[qb] + 8.0f));
      const float mold = mrow[qb];
      float mnew = mold;
      float fs = 1.0f;
      if (nskip) {
        mnew = fmaxf(mold, pm);
        fs = __expf(mold - mnew);
        mrow[qb] = mnew;
      }
      float ps = 0.f;
#pragma unroll
      for (int e = 0; e < 16; ++e) {
        pv[e] = __expf(pv[e] - mnew);
        ps += pv[e];
      }
      ps += __shfl_xor(ps, 16);
      ps += __shfl_xor(ps, 32);
      lrow[qb] = (nskip ? lrow[qb] * fs : lrow[qb]) + ps;
      int prow = qb * 16 + ci;
      int swp = ((prow ^ (prow >> 3)) & 7) << 4;
#pragma unroll
      for (int kvb = 0; kvb < 4; ++kvb) {
        bf16x4 pk;
#pragma unroll
        for (int r = 0; r < 4; ++r) pk[r] = (bf16_t)pv[kvb * 4 + r];
        *(bf16x4*)((char*)&Pl[w][0] + prow * 128 + (((kvb * 16 + 4 * g) * 2) ^ swp)) = pk;
      }
      if (nskip) {
        float fo[4];
#pragma unroll
        for (int r = 0; r < 4; ++r) fo[r] = __shfl(fs, 4 * g + r);
#pragma unroll
        for (int nb = 0; nb < 8; ++nb)
#pragma unroll
          for (int r = 0; r < 4; ++r) o[qb][nb][r] *= fo[r];
      }
    }
    bf16x8 pa[2][2];
#pragma unroll
    for (int qb = 0; qb < 2; ++qb) {
      if (!act[qb]) continue;
      int prow = qb * 16 + ci;
      int swp = ((prow ^ (prow >> 3)) & 7) << 4;
#pragma unroll
      for (int ks = 0; ks < 2; ++ks)
        pa[qb][ks] = *(const bf16x8*)((char*)&Pl[w][0] + prow * 128 + ((ks * 64 + g * 16) ^ swp));
    }
    __builtin_amdgcn_s_setprio(1);
#pragma unroll
    for (int nb = 0; nb < 8; ++nb) {
      int d = nb * 16 + ci;
      int sw = ((d ^ (d >> 3)) & 7) << 4;
      bf16x8 bv0 = *(const bf16x8*)((char*)Vt + d * 128 + ((g * 16) ^ sw));
      bf16x8 bv1 = *(const bf16x8*)((char*)Vt + d * 128 + ((64 + g * 16) ^ sw));
#pragma unroll
      for (int qb = 0; qb < 2; ++qb) {
        if (!act[qb]) continue;
        o[qb][nb] = MFMA16(pa[qb][0], bv0, o[qb][nb]);
        o[qb][nb] = MFMA16(pa[qb][1], bv1, o[qb][nb]);
      }
    }
    __builtin_amdgcn_s_setprio(0);
  }
#pragma unroll
  for (int qb = 0; qb < 2; ++qb) {
    float linv = 1.0f / lrow[qb];
    float lv[4];
#pragma unroll
    for (int r = 0; r < 4; ++r) lv[r] = __shfl(linv, 4 * g + r);
#pragma unroll
    for (int r = 0; r < 4; ++r) {
      int n = qr[qb] + 4 * g + r;
      bf16_t* op = O + (size_t)(b * 2048 + n) * 4096 + h * 128;
#pragma unroll
      for (int nb = 0; nb < 8; ++nb) op[nb * 16 + ci] = (bf16_t)(o[qb][nb][r] * lv[r]);
    }
  }
}

extern "C" void kernel_launch(void* const* d_in, const int* in_sizes, int n_in,
                              void* d_out, int out_size, void* d_ws, size_t ws_size,
                              hipStream_t stream) {
  (void)in_sizes; (void)n_in; (void)out_size; (void)ws_size;
  const float* X = (const float*)d_in[0];
  const int* pos = (const int*)d_in[1];
  const float* Wq = (const float*)d_in[2];
  const float* Wk = (const float*)d_in[3];
  const float* Wv = (const float*)d_in[4];
  const float* Wo = (const float*)d_in[5];
  float* out = (float*)d_out;

  char* w = (char*)d_ws;
  auto carve = [&](size_t bytes) {
    void* p = (void*)w;
    w += (bytes + 255) & ~(size_t)255;
    return p;
  };
  const size_t T = 4096;  // B*N tokens
  bf16_t* Xbf    = (bf16_t*)carve(T * 4096 * 2);
  bf16_t* WqkvT  = (bf16_t*)carve(6144ull * 4096 * 2);  // [Wq;Wk;Wv] transposed
  bf16_t* WoT    = (bf16_t*)carve(4096ull * 4096 * 2);
  bf16_t* QKVraw = (bf16_t*)carve(T * 6144 * 2);
  bf16_t* Qr     = (bf16_t*)carve(T * 4096 * 2);
  bf16_t* Kr     = (bf16_t*)carve(T * 1024 * 2);
  bf16_t* Vr     = (bf16_t*)carve(T * 1024 * 2);
  bf16_t* Obf    = (bf16_t*)carve(T * 4096 * 2);

  cvt_bf16<<<2048, 256, 0, stream>>>(X, Xbf, (int)(T * 4096 / 4));
  transpose_cvt<<<dim3(64, 64), 256, 0, stream>>>(Wq, WqkvT, 4096, 4096);
  transpose_cvt<<<dim3(16, 64), 256, 0, stream>>>(Wk, WqkvT + 4096ull * 4096, 4096, 1024);
  transpose_cvt<<<dim3(16, 64), 256, 0, stream>>>(Wv, WqkvT + 5120ull * 4096, 4096, 1024);
  transpose_cvt<<<dim3(64, 64), 256, 0, stream>>>(Wo, WoT, 4096, 4096);

  // fused QKV projection: [4096 tokens][6144], 16 x 32 tiles of 256x192 = 512 blocks
  gemm8qkv<<<512, 512, 0, stream>>>(Xbf, WqkvT, QKVraw, 6144, 4096, 32);

  rope_pack<<<(int)(T * 48 / 4), 256, 0, stream>>>(QKVraw, pos, Qr, Kr, Vr);

  attn_kernel<<<dim3(8, 64), 512, 0, stream>>>(Qr, Kr, Vr, Obf);

  // O projection: 16x16 tiles of 256^2 = 256 blocks (1 exact round)
  gemm8o<0><<<256, 512, 0, stream>>>(Obf, WoT, out, 4096, 4096, 16);
}